// Round 17
// baseline (251.206 us; speedup 1.0000x reference)
//
#include <hip/hip_runtime.h>
#include <hip/hip_bf16.h>

#define N_NODES 131072
#define N_EDGES 2097152
#define IN_DIM 768
#define HID 64
#define NPG 32
#define NGRAPH (N_NODES / NPG)   // 4096

#define BM 128
#define KC 32
#define NT (IN_DIM / KC)              // 24 K-steps
#define GEMM_BLOCKS (N_NODES / BM)    // 1024
#define GSPLIT 512                    // gemm blocks riding per fused launch

// ---- radix partition geometry: ranges of 128 nodes = 4 whole graphs ----
#define RNG 128
#define NB (N_NODES / RNG)            // 1024 buckets
#define EPB 4096                      // edges per count/scatter block
#define NCB (N_EDGES / EPB)           // 512 blocks
#define PBLK 8                        // prefix stage-A blocks
#define RPB (NCB / PBLK)              // 64 rows per stage-A block
#define PREP_BLK 192                  // blocks for W transpose

typedef __attribute__((ext_vector_type(8))) short bf16x8;
typedef __attribute__((ext_vector_type(4))) float f32x4;

static __device__ __forceinline__ unsigned short f2bf(float f) {
    __hip_bfloat16 h = __float2bfloat16(f);  // hardware RNE cvt
    return *reinterpret_cast<unsigned short*>(&h);
}
static __device__ __forceinline__ float bf2f(unsigned short s) {
    return __uint_as_float(((unsigned int)s) << 16);
}

// async 16B global -> LDS (no VGPR round-trip; size must be literal 16)
static __device__ __forceinline__ void gload_lds16(const float* g, float* l) {
    __builtin_amdgcn_global_load_lds(
        (const __attribute__((address_space(1))) void*)g,
        (__attribute__((address_space(3))) void*)l, 16, 0, 0);
}

// =================== device bodies ===================
// R16 double-buffered async GEMM, NO dinv fold (runs concurrent with sort2).
// xs points to 2*BM*KC floats of LDS (32 KB).
static __device__ __forceinline__ void dev_gemm_dbuf(int gb, const float* x,
                                                     const unsigned short* Wt,
                                                     unsigned short* hsb,
                                                     float* xs) {
    int tid = threadIdx.x;
    int lane = tid & 63;
    int w = tid >> 6;
    int rowbase = gb * BM;
    int rl = lane & 15;
    int kq = (lane >> 4) * 8;

    int jhi = lane >> 3, jlo = lane & 7;
    int cg = jlo ^ jhi;                          // swizzled global 16B-chunk
    const float* gbase = x + (size_t)rowbase * IN_DIM + cg * 4;
    const unsigned short* wp = Wt + (size_t)rl * IN_DIM + kq;

    int r0 = w * 32 + rl, r1 = r0 + 16;
    int swz = rl & 7;
    int G0 = (lane >> 4) * 2;

    f32x4 acc[2][4] = {};

    #pragma unroll
    for (int q = 0; q < 4; ++q) {
        int segq = w * 4 + q;
        gload_lds16(gbase + (size_t)(segq * 8 + jhi) * IN_DIM, xs + segq * 8 * KC);
    }
    __syncthreads();

    for (int t = 0; t < NT; ++t) {
        int cur = t & 1;
        if (t + 1 < NT) {   // issue next tile BEFORE compute (flies under it)
            float* bufn = xs + (cur ^ 1) * (BM * KC);
            #pragma unroll
            for (int q = 0; q < 4; ++q) {
                int segq = w * 4 + q;
                gload_lds16(gbase + (size_t)(segq * 8 + jhi) * IN_DIM + (t + 1) * KC,
                            bufn + segq * 8 * KC);
            }
        }
        const float4* xsf = (const float4*)(xs + cur * (BM * KC));
        float4 p0 = xsf[r0 * 8 + (G0 ^ swz)];
        float4 p1 = xsf[r0 * 8 + ((G0 + 1) ^ swz)];
        float4 p2 = xsf[r1 * 8 + (G0 ^ swz)];
        float4 p3 = xsf[r1 * 8 + ((G0 + 1) ^ swz)];
        int kb = t * KC;
        bf16x8 b0 = *(const bf16x8*)(wp + kb);
        bf16x8 b1 = *(const bf16x8*)(wp + (size_t)16 * IN_DIM + kb);
        bf16x8 b2 = *(const bf16x8*)(wp + (size_t)32 * IN_DIM + kb);
        bf16x8 b3 = *(const bf16x8*)(wp + (size_t)48 * IN_DIM + kb);
        bf16x8 a0, a1;
        a0[0] = (short)f2bf(p0.x); a0[1] = (short)f2bf(p0.y);
        a0[2] = (short)f2bf(p0.z); a0[3] = (short)f2bf(p0.w);
        a0[4] = (short)f2bf(p1.x); a0[5] = (short)f2bf(p1.y);
        a0[6] = (short)f2bf(p1.z); a0[7] = (short)f2bf(p1.w);
        a1[0] = (short)f2bf(p2.x); a1[1] = (short)f2bf(p2.y);
        a1[2] = (short)f2bf(p2.z); a1[3] = (short)f2bf(p2.w);
        a1[4] = (short)f2bf(p3.x); a1[5] = (short)f2bf(p3.y);
        a1[6] = (short)f2bf(p3.z); a1[7] = (short)f2bf(p3.w);
        acc[0][0] = __builtin_amdgcn_mfma_f32_16x16x32_bf16(a0, b0, acc[0][0], 0, 0, 0);
        acc[1][0] = __builtin_amdgcn_mfma_f32_16x16x32_bf16(a1, b0, acc[1][0], 0, 0, 0);
        acc[0][1] = __builtin_amdgcn_mfma_f32_16x16x32_bf16(a0, b1, acc[0][1], 0, 0, 0);
        acc[1][1] = __builtin_amdgcn_mfma_f32_16x16x32_bf16(a1, b1, acc[1][1], 0, 0, 0);
        acc[0][2] = __builtin_amdgcn_mfma_f32_16x16x32_bf16(a0, b2, acc[0][2], 0, 0, 0);
        acc[1][2] = __builtin_amdgcn_mfma_f32_16x16x32_bf16(a1, b2, acc[1][2], 0, 0, 0);
        acc[0][3] = __builtin_amdgcn_mfma_f32_16x16x32_bf16(a0, b3, acc[0][3], 0, 0, 0);
        acc[1][3] = __builtin_amdgcn_mfma_f32_16x16x32_bf16(a1, b3, acc[1][3], 0, 0, 0);
        __syncthreads();   // drains vmcnt(0): next tile resident; cur reusable
    }
    #pragma unroll
    for (int rt = 0; rt < 2; ++rt) {
        int row0 = rowbase + w * 32 + rt * 16 + (lane >> 4) * 4;
        #pragma unroll
        for (int ct = 0; ct < 4; ++ct)
            #pragma unroll
            for (int rr = 0; rr < 4; ++rr) {
                int col = ct * 16 + rl;
                hsb[(size_t)(row0 + rr) * HID + col] = f2bf(acc[rt][ct][rr]);
            }
    }
}

static __device__ __forceinline__ void dev_scatter(int cb, const int* src, const int* dst,
                                                   const unsigned int* C, const unsigned int* S,
                                                   const unsigned int* bstart,
                                                   unsigned int* part, unsigned int* off) {
    int tid = threadIdx.x;
    int p = cb >> 6;
    for (int t = tid; t < NB; t += 256)
        off[t] = bstart[t] + S[p * NB + t] + C[(size_t)cb * NB + t];
    __syncthreads();
    int base = cb * EPB;
    #pragma unroll
    for (int u = 0; u < EPB / 256; ++u) {
        int i = base + u * 256 + tid;
        int d = dst[i];
        unsigned int pos = atomicAdd(&off[d >> 7], 1u);
        part[pos] = (unsigned int)src[i] | ((unsigned int)(d & (RNG - 1)) << 17);
    }
}

static __device__ __forceinline__ void dev_sort2(int b, const unsigned int* part,
                                                 const unsigned int* bstart,
                                                 unsigned int* part2, unsigned int* nstart,
                                                 float* dinv, unsigned int* sm) {
    unsigned int* hist = sm;
    unsigned int* sc   = sm + RNG;
    unsigned int* off  = sm + 2 * RNG;
    int tid = threadIdx.x;
    if (tid < RNG) hist[tid] = 0u;
    __syncthreads();
    unsigned int s0 = bstart[b], s1 = bstart[b + 1];
    for (unsigned int j = s0 + tid; j < s1; j += 256)
        atomicAdd(&hist[part[j] >> 17], 1u);
    __syncthreads();
    if (tid < RNG) sc[tid] = hist[tid];
    __syncthreads();
    #pragma unroll
    for (int o = 1; o < RNG; o <<= 1) {
        unsigned int u = (tid < RNG && tid >= o) ? sc[tid - o] : 0u;
        __syncthreads();
        if (tid < RNG) sc[tid] += u;
        __syncthreads();
    }
    if (tid < RNG) {
        unsigned int excl = sc[tid] - hist[tid];
        nstart[b * RNG + tid] = s0 + excl;
        off[tid] = s0 + excl;
        dinv[b * RNG + tid] = rsqrtf((float)(hist[tid] + 1));
    }
    if (b == NB - 1 && tid == 0) nstart[N_NODES] = N_EDGES;
    __syncthreads();
    for (unsigned int j = s0 + tid; j < s1; j += 256) {
        unsigned int pr = part[j];
        unsigned int pos = atomicAdd(&off[pr >> 17], 1u);
        part2[pos] = pr & 0x1FFFF;
    }
}

// =================== kernels ===================
// k1: W transpose + per-block bucket histogram
__global__ __launch_bounds__(256) void gcn_prep_count(const float* __restrict__ W,
                                                      unsigned short* __restrict__ Wt,
                                                      const int* __restrict__ dst,
                                                      unsigned int* __restrict__ C) {
    __shared__ unsigned int hist[NB];
    int tid = threadIdx.x;
    if (blockIdx.x < PREP_BLK) {
        int i = blockIdx.x * 256 + tid;
        if (i < IN_DIM * HID) {
            int k = i >> 6, n = i & 63;
            Wt[n * IN_DIM + k] = f2bf(W[i]);
        }
        return;
    }
    int cb = blockIdx.x - PREP_BLK;
    for (int t = tid; t < NB; t += 256) hist[t] = 0u;
    __syncthreads();
    int base = cb * EPB;
    #pragma unroll
    for (int u = 0; u < EPB / 256; ++u) {
        int d = dst[base + u * 256 + tid];
        atomicAdd(&hist[d >> 7], 1u);   // native ds_add_u32: cheap
    }
    __syncthreads();
    for (int t = tid; t < NB; t += 256) C[(size_t)cb * NB + t] = hist[t];
}

// k2: prefix stage A
__global__ __launch_bounds__(256) void gcn_prefA(unsigned int* __restrict__ C,
                                                 unsigned int* __restrict__ S) {
    int tid = threadIdx.x;
    int p = blockIdx.x;
    #pragma unroll
    for (int c = 0; c < 4; ++c) {
        int t = tid + c * 256;
        unsigned int run = 0;
        for (int r = 0; r < RPB; r += 8) {
            unsigned int v[8];
            size_t base = ((size_t)(p * RPB + r)) * NB + t;
            #pragma unroll
            for (int j = 0; j < 8; ++j) v[j] = C[base + (size_t)j * NB];
            #pragma unroll
            for (int j = 0; j < 8; ++j) { C[base + (size_t)j * NB] = run; run += v[j]; }
        }
        S[p * NB + t] = run;
    }
}

// k3: prefix stage B
__global__ __launch_bounds__(256) void gcn_prefB(unsigned int* __restrict__ S,
                                                 unsigned int* __restrict__ bstart) {
    __shared__ unsigned int sm[256];
    int tid = threadIdx.x;
    unsigned int lexcl[4];
    unsigned int lrun = 0;
    #pragma unroll
    for (int j = 0; j < 4; ++j) {
        unsigned int t = tid * 4 + j;
        unsigned int r = 0;
        #pragma unroll
        for (int p = 0; p < PBLK; ++p) {
            unsigned int v = S[p * NB + t];
            S[p * NB + t] = r;
            r += v;
        }
        lexcl[j] = lrun;
        lrun += r;
    }
    sm[tid] = lrun;
    __syncthreads();
    for (int off = 1; off < 256; off <<= 1) {
        unsigned int u = (tid >= off) ? sm[tid - off] : 0u;
        __syncthreads();
        sm[tid] += u;
        __syncthreads();
    }
    unsigned int texcl = sm[tid] - lrun;
    #pragma unroll
    for (int j = 0; j < 4; ++j) bstart[tid * 4 + j] = texcl + lexcl[j];
    if (tid == 255) bstart[NB] = N_EDGES;
}

// k4: fusedA — gemm tiles [0,512) | scatter (branch fusion: disjoint paths,
// no occupancy clamp, no queue loop -> allocator takes max of paths; the
// async-LDS gemm keeps BW at 2 blocks/CU since in-flight bytes come from
// the gload_lds queue, not waves).
__global__ __launch_bounds__(256) void gcn_fusedA(const float* __restrict__ x,
                                                  const unsigned short* __restrict__ Wt,
                                                  unsigned short* __restrict__ hsb,
                                                  const int* __restrict__ src,
                                                  const int* __restrict__ dst,
                                                  const unsigned int* __restrict__ C,
                                                  const unsigned int* __restrict__ S,
                                                  const unsigned int* __restrict__ bstart,
                                                  unsigned int* __restrict__ part) {
    __shared__ __align__(16) float smem[2 * BM * KC];   // 32 KB union
    if ((int)blockIdx.x < GSPLIT) {
        dev_gemm_dbuf(blockIdx.x, x, Wt, hsb, smem);
    } else {
        dev_scatter(blockIdx.x - GSPLIT, src, dst, C, S, bstart, part,
                    (unsigned int*)smem);
    }
}

// k5: fusedB — gemm tiles [512,1024) | sort2
__global__ __launch_bounds__(256) void gcn_fusedB(const float* __restrict__ x,
                                                  const unsigned short* __restrict__ Wt,
                                                  unsigned short* __restrict__ hsb,
                                                  const unsigned int* __restrict__ part,
                                                  const unsigned int* __restrict__ bstart,
                                                  unsigned int* __restrict__ part2,
                                                  unsigned int* __restrict__ nstart,
                                                  float* __restrict__ dinv) {
    __shared__ __align__(16) float smem[2 * BM * KC];   // 32 KB union
    if ((int)blockIdx.x < GSPLIT) {
        dev_gemm_dbuf(GSPLIT + blockIdx.x, x, Wt, hsb, smem);
    } else {
        dev_sort2(blockIdx.x - GSPLIT, part, bstart, part2, nstart, dinv,
                  (unsigned int*)smem);
    }
}

// k6: agg — R10 4-node interleave + per-neighbor dinv via shfl (R13-proven)
__global__ __launch_bounds__(512) void gcn_agg(const unsigned short* __restrict__ hsb,
                                               const unsigned int* __restrict__ part2,
                                               const unsigned int* __restrict__ nstart,
                                               const float* __restrict__ dinv,
                                               const float* __restrict__ b_conv,
                                               const float* __restrict__ W_lin,
                                               const float* __restrict__ b_lin,
                                               float* __restrict__ out) {
    __shared__ float p0s[8], p1s[8];
    int tid = threadIdx.x, lane = tid & 63, w = tid >> 6;
    int g = blockIdx.x;
    float bc = b_conv[lane];
    float l0 = 0.f, l1 = 0.f;

    int i0 = g * NPG + w * 4;
    int cc[4];
    unsigned int stt[4];
    float dii[4];
    int sidx[4];
    float dsv[4];
    float av[4];
    #pragma unroll
    for (int k = 0; k < 4; ++k) {
        int i = i0 + k;
        unsigned int st = nstart[i], en = nstart[i + 1];
        stt[k] = st;
        cc[k] = (int)(en - st);
        dii[k] = dinv[i];
    }
    #pragma unroll
    for (int k = 0; k < 4; ++k) {
        sidx[k] = (lane < cc[k]) ? (int)part2[stt[k] + lane] : (i0 + k);
        dsv[k] = (lane < cc[k]) ? dinv[sidx[k]] : 0.f;
    }
    #pragma unroll
    for (int k = 0; k < 4; ++k)
        av[k] = dii[k] * bf2f(hsb[(size_t)(i0 + k) * HID + lane]);  // di*h_i

    int cmax = max(max(cc[0], cc[1]), max(cc[2], cc[3]));
    int clim = min(cmax, 64);
    for (int e = 0; e < clim; e += 4) {
        float v[4][4];
        #pragma unroll
        for (int k = 0; k < 4; ++k) {
            #pragma unroll
            for (int j = 0; j < 4; ++j) {
                int idx = e + j;
                int cl = idx < cc[k] ? idx : 0;     // clamp: dup load, L1 hit
                int s = __shfl(sidx[k], cl);
                float ds = __shfl(dsv[k], cl);
                v[k][j] = ds * bf2f(hsb[(size_t)s * HID + lane]);
            }
        }
        #pragma unroll
        for (int k = 0; k < 4; ++k) {
            #pragma unroll
            for (int j = 0; j < 4; ++j)
                if (e + j < cc[k]) av[k] += v[k][j]; // wave-uniform predicate
        }
    }
    // safety net for degree > 64 (never taken on this data; CAP=52 proof)
    #pragma unroll
    for (int k = 0; k < 4; ++k)
        for (int e2 = 64; e2 < cc[k]; ++e2) {
            int s = (int)part2[stt[k] + e2];
            av[k] += dinv[s] * bf2f(hsb[(size_t)s * HID + lane]);
        }

    #pragma unroll
    for (int k = 0; k < 4; ++k) {
        int node = w * 4 + k;
        float v = fmaxf(fmaf(av[k], dii[k], bc), 0.f);
        l0 = fmaf(v, W_lin[node * HID + lane], l0);
        l1 = fmaf(v, W_lin[HID * NPG + node * HID + lane], l1);
    }
    #pragma unroll
    for (int d = 32; d > 0; d >>= 1) {
        l0 += __shfl_down(l0, d);
        l1 += __shfl_down(l1, d);
    }
    if (lane == 0) { p0s[w] = l0; p1s[w] = l1; }
    __syncthreads();
    if (tid == 0) {
        float A = b_lin[0], B = b_lin[1];
        #pragma unroll
        for (int j = 0; j < 8; ++j) { A += p0s[j]; B += p1s[j]; }
        float m = fmaxf(A, B);
        float lse = m + logf(expf(A - m) + expf(B - m));
        out[g * 2 + 0] = A - lse;
        out[g * 2 + 1] = B - lse;
    }
}

extern "C" void kernel_launch(void* const* d_in, const int* in_sizes, int n_in,
                              void* d_out, int out_size, void* d_ws, size_t ws_size,
                              hipStream_t stream) {
    const float* x  = (const float*)d_in[0];
    const int* ei   = (const int*)d_in[1];
    const float* Wc = (const float*)d_in[2];
    const float* bc = (const float*)d_in[3];
    const float* Wl = (const float*)d_in[4];
    const float* bl = (const float*)d_in[5];
    float* out = (float*)d_out;

    char* ws = (char*)d_ws;
    unsigned short* Wt    = (unsigned short*)(ws);                // 96 KB
    float*          dinv  = (float*)(ws + (128 << 10));           // 512 KB
    unsigned int*  bstart = (unsigned int*)(ws + (640 << 10));    // 4.1 KB
    unsigned int*  S      = (unsigned int*)(ws + (656 << 10));    // 32 KB
    unsigned int*  part2  = (unsigned int*)(ws + (1u << 20));     // 8 MB
    unsigned int*  nstart = (unsigned int*)(ws + (9u << 20));     // 512 KB + 4
    unsigned int*  C      = (unsigned int*)(ws + (10u << 20));    // 2 MB
    unsigned int*  part   = (unsigned int*)(ws + (12u << 20));    // 8 MB
    unsigned short* hsb   = (unsigned short*)(ws + (20u << 20));  // 16 MB, own
    // region (hsb written CONCURRENTLY with C/part in fusedA). 36 MB total.

    const int* srcIdx = ei;
    const int* dstIdx = ei + N_EDGES;

    gcn_prep_count<<<PREP_BLK + NCB, 256, 0, stream>>>(Wc, Wt, dstIdx, C);
    gcn_prefA<<<PBLK, 256, 0, stream>>>(C, S);
    gcn_prefB<<<1, 256, 0, stream>>>(S, bstart);
    gcn_fusedA<<<GSPLIT + NCB, 256, 0, stream>>>(x, Wt, hsb, srcIdx, dstIdx,
                                                 C, S, bstart, part);
    gcn_fusedB<<<GSPLIT + NB, 256, 0, stream>>>(x, Wt, hsb, part, bstart,
                                                part2, nstart, dinv);
    gcn_agg<<<NGRAPH, 512, 0, stream>>>(hsb, part2, nstart, dinv, bc, Wl, bl, out);
}

// Round 18
// 223.069 us; speedup vs baseline: 1.1261x; 1.1261x over previous
//
#include <hip/hip_runtime.h>
#include <hip/hip_bf16.h>

#define N_NODES 131072
#define N_EDGES 2097152
#define IN_DIM 768
#define HID 64
#define NPG 32
#define NGRAPH (N_NODES / NPG)   // 4096

#define BM 128
#define KC 32
#define NT (IN_DIM / KC)              // 24 K-steps
#define GEMM_BLOCKS (N_NODES / BM)    // 1024

// ---- radix partition geometry: ranges of 128 nodes = 4 whole graphs ----
#define RNG 128
#define NB (N_NODES / RNG)            // 1024 buckets
#define EPB 4096                      // edges per count/scatter block
#define NCB (N_EDGES / EPB)           // 512 blocks
#define PBLK 8                        // prefix stage-A blocks
#define RPB (NCB / PBLK)              // 64 rows per stage-A block
#define PREP_BLK 192                  // blocks for W transpose

typedef __attribute__((ext_vector_type(8))) short bf16x8;
typedef __attribute__((ext_vector_type(4))) float f32x4;

static __device__ __forceinline__ unsigned short f2bf(float f) {
    __hip_bfloat16 h = __float2bfloat16(f);  // hardware RNE cvt
    return *reinterpret_cast<unsigned short*>(&h);
}
static __device__ __forceinline__ float bf2f(unsigned short s) {
    return __uint_as_float(((unsigned int)s) << 16);
}

// async 16B global -> LDS (no VGPR round-trip; size must be literal 16)
static __device__ __forceinline__ void gload_lds16(const float* g, float* l) {
    __builtin_amdgcn_global_load_lds(
        (const __attribute__((address_space(1))) void*)g,
        (__attribute__((address_space(3))) void*)l, 16, 0, 0);
}
static __device__ __forceinline__ void gload_lds16w(const unsigned short* g,
                                                    unsigned short* l) {
    __builtin_amdgcn_global_load_lds(
        (const __attribute__((address_space(1))) void*)g,
        (__attribute__((address_space(3))) void*)l, 16, 0, 0);
}

// ---- k1: W transpose (blocks < PREP_BLK) + per-block bucket histogram ----
__global__ __launch_bounds__(256) void gcn_prep_count(const float* __restrict__ W,
                                                      unsigned short* __restrict__ Wt,
                                                      const int* __restrict__ dst,
                                                      unsigned int* __restrict__ C) {
    __shared__ unsigned int hist[NB];
    int tid = threadIdx.x;
    if (blockIdx.x < PREP_BLK) {
        int i = blockIdx.x * 256 + tid;
        if (i < IN_DIM * HID) {
            int k = i >> 6, n = i & 63;
            Wt[n * IN_DIM + k] = f2bf(W[i]);
        }
        return;
    }
    int cb = blockIdx.x - PREP_BLK;
    for (int t = tid; t < NB; t += 256) hist[t] = 0u;
    __syncthreads();
    int base = cb * EPB;
    #pragma unroll
    for (int u = 0; u < EPB / 256; ++u) {
        int d = dst[base + u * 256 + tid];
        atomicAdd(&hist[d >> 7], 1u);   // native ds_add_u32: cheap (R10 ledger)
    }
    __syncthreads();
    for (int t = tid; t < NB; t += 256) C[(size_t)cb * NB + t] = hist[t];
}

// ---- k2: prefix stage A ----
__global__ __launch_bounds__(256) void gcn_prefA(unsigned int* __restrict__ C,
                                                 unsigned int* __restrict__ S) {
    int tid = threadIdx.x;
    int p = blockIdx.x;
    #pragma unroll
    for (int c = 0; c < 4; ++c) {
        int t = tid + c * 256;
        unsigned int run = 0;
        for (int r = 0; r < RPB; r += 8) {
            unsigned int v[8];
            size_t base = ((size_t)(p * RPB + r)) * NB + t;
            #pragma unroll
            for (int j = 0; j < 8; ++j) v[j] = C[base + (size_t)j * NB];
            #pragma unroll
            for (int j = 0; j < 8; ++j) { C[base + (size_t)j * NB] = run; run += v[j]; }
        }
        S[p * NB + t] = run;
    }
}

// ---- k3: prefix stage B (256-thread, proven R6-R16) ----
__global__ __launch_bounds__(256) void gcn_prefB(unsigned int* __restrict__ S,
                                                 unsigned int* __restrict__ bstart) {
    __shared__ unsigned int sm[256];
    int tid = threadIdx.x;
    unsigned int lexcl[4];
    unsigned int lrun = 0;
    #pragma unroll
    for (int j = 0; j < 4; ++j) {
        unsigned int t = tid * 4 + j;
        unsigned int r = 0;
        #pragma unroll
        for (int p = 0; p < PBLK; ++p) {
            unsigned int v = S[p * NB + t];
            S[p * NB + t] = r;
            r += v;
        }
        lexcl[j] = lrun;
        lrun += r;
    }
    sm[tid] = lrun;
    __syncthreads();
    for (int off = 1; off < 256; off <<= 1) {
        unsigned int u = (tid >= off) ? sm[tid - off] : 0u;
        __syncthreads();
        sm[tid] += u;
        __syncthreads();
    }
    unsigned int texcl = sm[tid] - lrun;
    #pragma unroll
    for (int j = 0; j < 4; ++j) bstart[tid * 4 + j] = texcl + lexcl[j];
    if (tid == 255) bstart[NB] = N_EDGES;
}

// ---- k4: scatter edges into bucket-contiguous order (LDS ticketing) ----
__global__ __launch_bounds__(256) void gcn_scatter(const int* __restrict__ src,
                                                   const int* __restrict__ dst,
                                                   const unsigned int* __restrict__ C,
                                                   const unsigned int* __restrict__ S,
                                                   const unsigned int* __restrict__ bstart,
                                                   unsigned int* __restrict__ part) {
    __shared__ unsigned int off[NB];
    int tid = threadIdx.x, cb = blockIdx.x;
    int p = cb >> 6;
    for (int t = tid; t < NB; t += 256)
        off[t] = bstart[t] + S[p * NB + t] + C[(size_t)cb * NB + t];
    __syncthreads();
    int base = cb * EPB;
    #pragma unroll
    for (int u = 0; u < EPB / 256; ++u) {
        int i = base + u * 256 + tid;
        int d = dst[i];
        unsigned int pos = atomicAdd(&off[d >> 7], 1u);
        part[pos] = (unsigned int)src[i] | ((unsigned int)(d & (RNG - 1)) << 17);
    }
}

// ---- k5: second-level sort -> per-node CSR (part2, nstart) + dinv ----
__global__ __launch_bounds__(256) void gcn_sort2(const unsigned int* __restrict__ part,
                                                 const unsigned int* __restrict__ bstart,
                                                 unsigned int* __restrict__ part2,
                                                 unsigned int* __restrict__ nstart,
                                                 float* __restrict__ dinv) {
    __shared__ unsigned int hist[RNG];
    __shared__ unsigned int sc[RNG];
    __shared__ unsigned int off[RNG];
    int tid = threadIdx.x, b = blockIdx.x;
    if (tid < RNG) hist[tid] = 0u;
    __syncthreads();
    unsigned int s0 = bstart[b], s1 = bstart[b + 1];
    for (unsigned int j = s0 + tid; j < s1; j += 256)
        atomicAdd(&hist[part[j] >> 17], 1u);
    __syncthreads();
    if (tid < RNG) sc[tid] = hist[tid];
    __syncthreads();
    #pragma unroll
    for (int o = 1; o < RNG; o <<= 1) {
        unsigned int u = (tid < RNG && tid >= o) ? sc[tid - o] : 0u;
        __syncthreads();
        if (tid < RNG) sc[tid] += u;
        __syncthreads();
    }
    if (tid < RNG) {
        unsigned int excl = sc[tid] - hist[tid];
        nstart[b * RNG + tid] = s0 + excl;
        off[tid] = s0 + excl;
        dinv[b * RNG + tid] = rsqrtf((float)(hist[tid] + 1));
    }
    if (b == NB - 1 && tid == 0) nstart[N_NODES] = N_EDGES;
    __syncthreads();
    for (unsigned int j = s0 + tid; j < s1; j += 256) {
        unsigned int pr = part[j];
        unsigned int pos = atomicAdd(&off[pr >> 17], 1u);
        part2[pos] = pr & 0x1FFFF;
    }
}

// ---- k6: bf16 GEMM, async LDS dbuf, B ALSO STAGED IN LDS (R16 -> R18) ----
// R16 weak-gain autopsy: vmcnt is IN-ORDER; B's 4 global loads inside
// compute are issued after the next tile's global_load_lds batch, so the
// compiler's wait-for-B drains the staged loads too -- overlap nullified.
// Fix: stage B (64x32 bf16 = 4KB/step, 1 gload_lds16 per thread) so the
// compute phase is VMEM-FREE (only ds_read/lgkmcnt). The sole vmcnt(0)
// drain is the barrier AFTER compute. LDS 2x(16+4)=40KB -> 4 blocks/CU.
// B's L2 traffic also drops 4x (per-block not per-wave staging).
__global__ __launch_bounds__(256) void gcn_gemm(const float* __restrict__ x,
                                                const unsigned short* __restrict__ Wt,
                                                const float* __restrict__ dinv,
                                                unsigned short* __restrict__ hsb) {
    __shared__ __align__(16) float xs[2][BM][KC];            // 32 KB
    __shared__ __align__(16) unsigned short bs[2][64 * KC];  // 8 KB
    int tid = threadIdx.x;
    int lane = tid & 63;
    int w = tid >> 6;
    int rowbase = blockIdx.x * BM;
    int rl = lane & 15;
    int kq = (lane >> 4) * 8;

    int jhi = lane >> 3, jlo = lane & 7;
    int cg = jlo ^ jhi;                          // swizzled global 16B-chunk
    const float* gbase = x + (size_t)rowbase * IN_DIM + cg * 4;
    // B staging: wave w stages Wt rows [w*16,(w+1)*16); lane j covers
    // row w*16+(j>>2), quarter j&3 (16B). LDS linear dest matches
    // row-major [64][32]bf16 with wave base w*1024B.
    const unsigned short* wgb = Wt + (size_t)(w * 16 + (lane >> 2)) * IN_DIM
                                   + (lane & 3) * 8;

    int r0 = w * 32 + rl, r1 = r0 + 16;
    int swz = rl & 7;
    int G0 = (lane >> 4) * 2;

    f32x4 acc[2][4] = {};

    // prologue: stage tile 0 (x + B) into buf 0
    #pragma unroll
    for (int q = 0; q < 4; ++q) {
        int segq = w * 4 + q;
        gload_lds16(gbase + (size_t)(segq * 8 + jhi) * IN_DIM, &xs[0][segq * 8][0]);
    }
    gload_lds16w(wgb, &bs[0][w * 512]);
    __syncthreads();

    for (int t = 0; t < NT; ++t) {
        int cur = t & 1;
        if (t + 1 < NT) {   // issue next tile BEFORE compute (flies under it)
            #pragma unroll
            for (int q = 0; q < 4; ++q) {
                int segq = w * 4 + q;
                gload_lds16(gbase + (size_t)(segq * 8 + jhi) * IN_DIM + (t + 1) * KC,
                            &xs[cur ^ 1][segq * 8][0]);
            }
            gload_lds16w(wgb + (t + 1) * KC, &bs[cur ^ 1][w * 512]);
        }
        const float4* xsf = (const float4*)xs[cur];
        float4 p0 = xsf[r0 * 8 + (G0 ^ swz)];
        float4 p1 = xsf[r0 * 8 + ((G0 + 1) ^ swz)];
        float4 p2 = xsf[r1 * 8 + (G0 ^ swz)];
        float4 p3 = xsf[r1 * 8 + ((G0 + 1) ^ swz)];
        bf16x8 b0 = *(const bf16x8*)&bs[cur][(0  + rl) * KC + kq];
        bf16x8 b1 = *(const bf16x8*)&bs[cur][(16 + rl) * KC + kq];
        bf16x8 b2 = *(const bf16x8*)&bs[cur][(32 + rl) * KC + kq];
        bf16x8 b3 = *(const bf16x8*)&bs[cur][(48 + rl) * KC + kq];
        bf16x8 a0, a1;
        a0[0] = (short)f2bf(p0.x); a0[1] = (short)f2bf(p0.y);
        a0[2] = (short)f2bf(p0.z); a0[3] = (short)f2bf(p0.w);
        a0[4] = (short)f2bf(p1.x); a0[5] = (short)f2bf(p1.y);
        a0[6] = (short)f2bf(p1.z); a0[7] = (short)f2bf(p1.w);
        a1[0] = (short)f2bf(p2.x); a1[1] = (short)f2bf(p2.y);
        a1[2] = (short)f2bf(p2.z); a1[3] = (short)f2bf(p2.w);
        a1[4] = (short)f2bf(p3.x); a1[5] = (short)f2bf(p3.y);
        a1[6] = (short)f2bf(p3.z); a1[7] = (short)f2bf(p3.w);
        acc[0][0] = __builtin_amdgcn_mfma_f32_16x16x32_bf16(a0, b0, acc[0][0], 0, 0, 0);
        acc[1][0] = __builtin_amdgcn_mfma_f32_16x16x32_bf16(a1, b0, acc[1][0], 0, 0, 0);
        acc[0][1] = __builtin_amdgcn_mfma_f32_16x16x32_bf16(a0, b1, acc[0][1], 0, 0, 0);
        acc[1][1] = __builtin_amdgcn_mfma_f32_16x16x32_bf16(a1, b1, acc[1][1], 0, 0, 0);
        acc[0][2] = __builtin_amdgcn_mfma_f32_16x16x32_bf16(a0, b2, acc[0][2], 0, 0, 0);
        acc[1][2] = __builtin_amdgcn_mfma_f32_16x16x32_bf16(a1, b2, acc[1][2], 0, 0, 0);
        acc[0][3] = __builtin_amdgcn_mfma_f32_16x16x32_bf16(a0, b3, acc[0][3], 0, 0, 0);
        acc[1][3] = __builtin_amdgcn_mfma_f32_16x16x32_bf16(a1, b3, acc[1][3], 0, 0, 0);
        __syncthreads();   // drains vmcnt(0): next tile resident; cur reusable
    }
    #pragma unroll
    for (int rt = 0; rt < 2; ++rt) {
        int row0 = rowbase + w * 32 + rt * 16 + (lane >> 4) * 4;
        #pragma unroll
        for (int rr = 0; rr < 4; ++rr) {
            float dv = dinv[row0 + rr];
            #pragma unroll
            for (int ct = 0; ct < 4; ++ct) {
                int col = ct * 16 + rl;
                hsb[(size_t)(row0 + rr) * HID + col] = f2bf(acc[rt][ct][rr] * dv);
            }
        }
    }
}

// ---- k7: CSR aggregation + relu + W_lin + per-graph logsoftmax ----
// R10's proven structure: 4-node interleave, 4-edge groups (16 gathers in
// flight/wave). R11 showed deeper ILP regresses on VGPR; keep as-is.
__global__ __launch_bounds__(512) void gcn_agg(const unsigned short* __restrict__ hsb,
                                               const unsigned int* __restrict__ part2,
                                               const unsigned int* __restrict__ nstart,
                                               const float* __restrict__ dinv,
                                               const float* __restrict__ b_conv,
                                               const float* __restrict__ W_lin,
                                               const float* __restrict__ b_lin,
                                               float* __restrict__ out) {
    __shared__ float p0s[8], p1s[8];
    int tid = threadIdx.x, lane = tid & 63, w = tid >> 6;
    int g = blockIdx.x;
    float bc = b_conv[lane];
    float l0 = 0.f, l1 = 0.f;

    int i0 = g * NPG + w * 4;                 // first of this wave's 4 nodes
    int cc[4];
    unsigned int stt[4];
    float dii[4];
    int sidx[4];
    float av[4];
    #pragma unroll
    for (int k = 0; k < 4; ++k) {
        int i = i0 + k;
        unsigned int st = nstart[i], en = nstart[i + 1];
        stt[k] = st;
        cc[k] = (int)(en - st);
        dii[k] = dinv[i];
    }
    #pragma unroll
    for (int k = 0; k < 4; ++k)
        sidx[k] = (lane < cc[k]) ? (int)part2[stt[k] + lane] : (i0 + k);
    #pragma unroll
    for (int k = 0; k < 4; ++k)
        av[k] = bf2f(hsb[(size_t)(i0 + k) * HID + lane]);   // self term

    int cmax = max(max(cc[0], cc[1]), max(cc[2], cc[3]));
    int clim = min(cmax, 64);
    for (int e = 0; e < clim; e += 4) {
        float v[4][4];
        #pragma unroll
        for (int k = 0; k < 4; ++k) {
            #pragma unroll
            for (int j = 0; j < 4; ++j) {
                int idx = e + j;
                int cl = idx < cc[k] ? idx : 0;     // clamp: dup load, L1 hit
                int s = __shfl(sidx[k], cl);
                v[k][j] = bf2f(hsb[(size_t)s * HID + lane]);
            }
        }
        #pragma unroll
        for (int k = 0; k < 4; ++k) {
            #pragma unroll
            for (int j = 0; j < 4; ++j)
                if (e + j < cc[k]) av[k] += v[k][j]; // wave-uniform predicate
        }
    }
    // safety net for degree > 64 (never taken on this data; CAP=52 proof)
    #pragma unroll
    for (int k = 0; k < 4; ++k)
        for (int e2 = 64; e2 < cc[k]; ++e2)
            av[k] += bf2f(hsb[(size_t)part2[stt[k] + e2] * HID + lane]);

    #pragma unroll
    for (int k = 0; k < 4; ++k) {
        int node = w * 4 + k;
        float v = fmaxf(fmaf(av[k], dii[k], bc), 0.f);
        l0 = fmaf(v, W_lin[node * HID + lane], l0);
        l1 = fmaf(v, W_lin[HID * NPG + node * HID + lane], l1);
    }
    #pragma unroll
    for (int d = 32; d > 0; d >>= 1) {
        l0 += __shfl_down(l0, d);
        l1 += __shfl_down(l1, d);
    }
    if (lane == 0) { p0s[w] = l0; p1s[w] = l1; }
    __syncthreads();
    if (tid == 0) {
        float A = b_lin[0], B = b_lin[1];
        #pragma unroll
        for (int j = 0; j < 8; ++j) { A += p0s[j]; B += p1s[j]; }
        float m = fmaxf(A, B);
        float lse = m + logf(expf(A - m) + expf(B - m));
        out[g * 2 + 0] = A - lse;
        out[g * 2 + 1] = B - lse;
    }
}

extern "C" void kernel_launch(void* const* d_in, const int* in_sizes, int n_in,
                              void* d_out, int out_size, void* d_ws, size_t ws_size,
                              hipStream_t stream) {
    const float* x  = (const float*)d_in[0];
    const int* ei   = (const int*)d_in[1];
    const float* Wc = (const float*)d_in[2];
    const float* bc = (const float*)d_in[3];
    const float* Wl = (const float*)d_in[4];
    const float* bl = (const float*)d_in[5];
    float* out = (float*)d_out;

    char* ws = (char*)d_ws;
    unsigned short* Wt   = (unsigned short*)(ws);                 // 96 KB
    float*          dinv = (float*)(ws + (128 << 10));            // 512 KB
    unsigned int*  bstart= (unsigned int*)(ws + (640 << 10));     // 4.1 KB
    unsigned int*  S     = (unsigned int*)(ws + (656 << 10));     // 32 KB
    unsigned int*  part2 = (unsigned int*)(ws + (1u << 20));      // 8 MB -> 9M
    unsigned int*  nstart= (unsigned int*)(ws + (9u << 20));      // 512 KB + 4
    unsigned int*  C     = (unsigned int*)(ws + (10u << 20));     // 2 MB -> 12M
    unsigned int*  part  = (unsigned int*)(ws + (12u << 20));     // 8 MB -> 20M
    unsigned short* hsb  = (unsigned short*)(ws + (10u << 20));   // 16 MB -> 26M
    // hsb OVERLAYS C+part: both dead after sort2; gemm (writer) runs after.

    const int* srcIdx = ei;
    const int* dstIdx = ei + N_EDGES;

    gcn_prep_count<<<PREP_BLK + NCB, 256, 0, stream>>>(Wc, Wt, dstIdx, C);
    gcn_prefA<<<PBLK, 256, 0, stream>>>(C, S);
    gcn_prefB<<<1, 256, 0, stream>>>(S, bstart);
    gcn_scatter<<<NCB, 256, 0, stream>>>(srcIdx, dstIdx, C, S, bstart, part);
    gcn_sort2<<<NB, 256, 0, stream>>>(part, bstart, part2, nstart, dinv);
    gcn_gemm<<<GEMM_BLOCKS, 256, 0, stream>>>(x, Wt, dinv, hsb);
    gcn_agg<<<NGRAPH, 512, 0, stream>>>(hsb, part2, nstart, dinv, bc, Wl, bl, out);
}